// Round 1
// baseline (628.274 us; speedup 1.0000x reference)
//
#include <hip/hip_runtime.h>
#include <math.h>

#define H_ 256
#define W_ 256
#define HW_ 65536
#define BHW_ 131072   // B*H*W, B=2
#define CCH 64        // C = G*CG = 64
#define NPC 8388608   // BHW_*64

__device__ __forceinline__ float geluf(float x) {
    const float k0 = 0.7978845608028654f; // sqrt(2/pi)
    return 0.5f * x * (1.f + tanhf(k0 * (x + 0.044715f * x * x * x)));
}
__device__ __forceinline__ float siluf(float x) {
    return x / (1.f + expf(-x));
}

// ---------- Poisson: divergence + u0 init ----------
// gx = -(x5+x6)*0.5 ; gy = (x5-x6)*0.5
// div = gx(h,w) - gx(h,w-1)[0 at w=0] + gy(h,w) - gy(h-1,w)[0 at h=0]
__global__ void k_div(const float* __restrict__ x, float* __restrict__ div, float* __restrict__ u0) {
    int pix = blockIdx.x * blockDim.x + threadIdx.x;
    if (pix >= BHW_) return;
    int b = pix >> 16, hw = pix & 65535;
    int h = hw >> 8, w = hw & 255;
    const float* x5 = x + ((size_t)(b * 9 + 5) << 16);
    const float* x6 = x + ((size_t)(b * 9 + 6) << 16);
    int i00 = (h << 8) + w;
    float gx = -0.5f * (x5[i00] + x6[i00]);
    float gy =  0.5f * (x5[i00] - x6[i00]);
    float d = gx + gy;
    if (w > 0) {
        int il = i00 - 1;
        d -= -0.5f * (x5[il] + x6[il]);
    }
    if (h > 0) {
        int iu = i00 - 256;
        d -=  0.5f * (x5[iu] - x6[iu]);
    }
    div[pix] = d;
    u0[pix] = 0.f;
}

// one Jacobi step with edge-clamped neighbors
__global__ void k_jacobi(const float* __restrict__ u, const float* __restrict__ div,
                         float* __restrict__ un) {
    int pix = blockIdx.x * blockDim.x + threadIdx.x;
    if (pix >= BHW_) return;
    int b = pix >> 16, hw = pix & 65535;
    int h = hw >> 8, w = hw & 255;
    const float* ub = u + ((size_t)b << 16);
    int hm = (h > 0) ? h - 1 : 0;
    int hp = (h < 255) ? h + 1 : 255;
    int wm = (w > 0) ? w - 1 : 0;
    int wp = (w < 255) ? w + 1 : 255;
    float nbr = ub[(hm << 8) + w] + ub[(hp << 8) + w] + ub[(h << 8) + wm] + ub[(h << 8) + wp];
    un[pix] = (nbr - div[pix]) * 0.25f;
}

// ---------- recon convnet ----------
// conv1: 7 -> 32, 3x3 SAME zero-pad, silu
__global__ void k_conv1(const float* __restrict__ x, const float* __restrict__ wgt,
                        const float* __restrict__ bias, float* __restrict__ out) {
    __shared__ float ws[32 * 7 * 9];
    __shared__ float bs[32];
    for (int i = threadIdx.x; i < 32 * 7 * 9; i += blockDim.x) ws[i] = wgt[i];
    if (threadIdx.x < 32) bs[threadIdx.x] = bias[threadIdx.x];
    __syncthreads();
    int pix = blockIdx.x * blockDim.x + threadIdx.x;
    if (pix >= BHW_) return;
    int b = pix >> 16, hw = pix & 65535;
    int h = hw >> 8, w = hw & 255;
    float acc[32];
    #pragma unroll
    for (int o = 0; o < 32; ++o) acc[o] = bs[o];
    for (int kh = 0; kh < 3; ++kh) {
        int y = h + kh - 1;
        if ((unsigned)y >= 256u) continue;
        for (int kw = 0; kw < 3; ++kw) {
            int xx = w + kw - 1;
            if ((unsigned)xx >= 256u) continue;
            for (int ci = 0; ci < 7; ++ci) {
                float v = x[((size_t)(b * 9 + ci) << 16) + (y << 8) + xx];
                int wb = ci * 9 + kh * 3 + kw;
                #pragma unroll
                for (int o = 0; o < 32; ++o) acc[o] += v * ws[o * 63 + wb];
            }
        }
    }
    for (int o = 0; o < 32; ++o)
        out[((size_t)(b * 32 + o) << 16) + hw] = siluf(acc[o]);
}

// conv2: 32 -> 32, silu
__global__ void k_conv2(const float* __restrict__ in, const float* __restrict__ wgt,
                        const float* __restrict__ bias, float* __restrict__ out) {
    __shared__ float ws[32 * 32 * 9];
    __shared__ float bs[32];
    for (int i = threadIdx.x; i < 32 * 32 * 9; i += blockDim.x) ws[i] = wgt[i];
    if (threadIdx.x < 32) bs[threadIdx.x] = bias[threadIdx.x];
    __syncthreads();
    int pix = blockIdx.x * blockDim.x + threadIdx.x;
    if (pix >= BHW_) return;
    int b = pix >> 16, hw = pix & 65535;
    int h = hw >> 8, w = hw & 255;
    float acc[32];
    #pragma unroll
    for (int o = 0; o < 32; ++o) acc[o] = bs[o];
    for (int kh = 0; kh < 3; ++kh) {
        int y = h + kh - 1;
        if ((unsigned)y >= 256u) continue;
        for (int kw = 0; kw < 3; ++kw) {
            int xx = w + kw - 1;
            if ((unsigned)xx >= 256u) continue;
            for (int ci = 0; ci < 32; ++ci) {
                float v = in[((size_t)(b * 32 + ci) << 16) + (y << 8) + xx];
                int wb = ci * 9 + kh * 3 + kw;
                #pragma unroll
                for (int o = 0; o < 32; ++o) acc[o] += v * ws[o * 288 + wb];
            }
        }
    }
    for (int o = 0; o < 32; ++o)
        out[((size_t)(b * 32 + o) << 16) + hw] = siluf(acc[o]);
}

// conv3: 32 -> 3, no activation
__global__ void k_conv3(const float* __restrict__ in, const float* __restrict__ wgt,
                        const float* __restrict__ bias, float* __restrict__ out) {
    __shared__ float ws[3 * 32 * 9];
    __shared__ float bs[3];
    for (int i = threadIdx.x; i < 3 * 32 * 9; i += blockDim.x) ws[i] = wgt[i];
    if (threadIdx.x < 3) bs[threadIdx.x] = bias[threadIdx.x];
    __syncthreads();
    int pix = blockIdx.x * blockDim.x + threadIdx.x;
    if (pix >= BHW_) return;
    int b = pix >> 16, hw = pix & 65535;
    int h = hw >> 8, w = hw & 255;
    float acc[3];
    #pragma unroll
    for (int o = 0; o < 3; ++o) acc[o] = bs[o];
    for (int kh = 0; kh < 3; ++kh) {
        int y = h + kh - 1;
        if ((unsigned)y >= 256u) continue;
        for (int kw = 0; kw < 3; ++kw) {
            int xx = w + kw - 1;
            if ((unsigned)xx >= 256u) continue;
            for (int ci = 0; ci < 32; ++ci) {
                float v = in[((size_t)(b * 32 + ci) << 16) + (y << 8) + xx];
                int wb = ci * 9 + kh * 3 + kw;
                #pragma unroll
                for (int o = 0; o < 3; ++o) acc[o] += v * ws[o * 288 + wb];
            }
        }
    }
    for (int o = 0; o < 3; ++o)
        out[((size_t)(b * 3 + o) << 16) + hw] = acc[o];
}

// ---------- a = gelu(guide @ W_aop + b_aop), NHWC ----------
// guide channels: [x7, x8, x5, x6]
__global__ void k_aproj(const float* __restrict__ x, const float* __restrict__ W,
                        const float* __restrict__ bias, float* __restrict__ a) {
    int idx = blockIdx.x * blockDim.x + threadIdx.x;
    if (idx >= NPC) return;
    int pix = idx >> 6, c = idx & 63;
    int b = pix >> 16, hw = pix & 65535;
    float g0 = x[((size_t)(b * 9 + 7) << 16) + hw];
    float g1 = x[((size_t)(b * 9 + 8) << 16) + hw];
    float g2 = x[((size_t)(b * 9 + 5) << 16) + hw];
    float g3 = x[((size_t)(b * 9 + 6) << 16) + hw];
    float v = bias[c] + g0 * W[c] + g1 * W[64 + c] + g2 * W[128 + c] + g3 * W[192 + c];
    a[idx] = geluf(v);
}

// depthwise 3x3 SAME zero-pad + gelu, NHWC; dw layout (kh,kw,1,C)
__global__ void k_dw(const float* __restrict__ a, const float* __restrict__ dw,
                     float* __restrict__ a2) {
    int idx = blockIdx.x * blockDim.x + threadIdx.x;
    if (idx >= NPC) return;
    int pix = idx >> 6, c = idx & 63;
    int b = pix >> 16, hw = pix & 65535;
    int h = hw >> 8, w = hw & 255;
    float s = 0.f;
    for (int kh = 0; kh < 3; ++kh) {
        int y = h + kh - 1;
        if ((unsigned)y >= 256u) continue;
        for (int kw = 0; kw < 3; ++kw) {
            int xx = w + kw - 1;
            if ((unsigned)xx >= 256u) continue;
            s += a[(((size_t)(b << 16) + (y << 8) + xx) << 6) + c] * dw[(kh * 3 + kw) * 64 + c];
        }
    }
    a2[idx] = geluf(s);
}

// xg = core @ W_in + b_in, NHWC ; core = [x0,x1,x2, gray, recon0..2]
__global__ void k_xproj(const float* __restrict__ x, const float* __restrict__ gray,
                        const float* __restrict__ recon, const float* __restrict__ W,
                        const float* __restrict__ bias, float* __restrict__ xg) {
    int idx = blockIdx.x * blockDim.x + threadIdx.x;
    if (idx >= NPC) return;
    int pix = idx >> 6, c = idx & 63;
    int b = pix >> 16, hw = pix & 65535;
    float c0 = x[((size_t)(b * 9 + 0) << 16) + hw];
    float c1 = x[((size_t)(b * 9 + 1) << 16) + hw];
    float c2 = x[((size_t)(b * 9 + 2) << 16) + hw];
    float c3 = gray[pix];
    float c4 = recon[((size_t)(b * 3 + 0) << 16) + hw];
    float c5 = recon[((size_t)(b * 3 + 1) << 16) + hw];
    float c6 = recon[((size_t)(b * 3 + 2) << 16) + hw];
    float v = bias[c] + c0 * W[c] + c1 * W[64 + c] + c2 * W[128 + c] + c3 * W[192 + c]
            + c4 * W[256 + c] + c5 * W[320 + c] + c6 * W[384 + c];
    xg[idx] = v;
}

// ---------- DCNv3 core: off/mask proj + softmax + bilinear gather + out proj ----------
// block = 256 threads = 4 pixels x 64 lanes
__global__ void k_dcn(const float* __restrict__ a2, const float* __restrict__ xg,
                      const float* __restrict__ Woff, const float* __restrict__ boff,
                      const float* __restrict__ Wmask, const float* __restrict__ bmask,
                      const float* __restrict__ Wout, const float* __restrict__ bout,
                      float* __restrict__ out) {
    __shared__ float a2s[4][64];
    __shared__ float offs[4][72];
    __shared__ float ms[4][36];
    __shared__ float accs[4][64];
    __shared__ float outs[4][65];   // padded: conflict-free transposed read

    int tid = threadIdx.x;
    int lp = tid >> 6;
    int lane = tid & 63;
    int pix = blockIdx.x * 4 + lp;

    a2s[lp][lane] = a2[((size_t)pix << 6) + lane];
    __syncthreads();

    // off[0..63]
    {
        float acc = boff[lane];
        #pragma unroll 8
        for (int c = 0; c < 64; ++c) acc += a2s[lp][c] * Woff[c * 72 + lane];
        offs[lp][lane] = acc;
    }
    // off[64..71] and mask logits[0..35]
    if (lane < 8) {
        int j = 64 + lane;
        float acc = boff[j];
        #pragma unroll 8
        for (int c = 0; c < 64; ++c) acc += a2s[lp][c] * Woff[c * 72 + j];
        offs[lp][j] = acc;
    } else if (lane < 44) {
        int j = lane - 8;
        float acc = bmask[j];
        #pragma unroll 8
        for (int c = 0; c < 64; ++c) acc += a2s[lp][c] * Wmask[c * 36 + j];
        ms[lp][j] = acc;
    }
    __syncthreads();

    // softmax over K per group (lanes 0..3)
    if (lane < 4) {
        int g = lane;
        float mx = -1e30f;
        #pragma unroll
        for (int k = 0; k < 9; ++k) mx = fmaxf(mx, ms[lp][g * 9 + k]);
        float e[9], s = 0.f;
        #pragma unroll
        for (int k = 0; k < 9; ++k) { e[k] = expf(ms[lp][g * 9 + k] - mx); s += e[k]; }
        float inv = 1.f / s;
        #pragma unroll
        for (int k = 0; k < 9; ++k) ms[lp][g * 9 + k] = e[k] * inv;
    }
    __syncthreads();

    // bilinear sampling: lane = g*16 + cg
    int g = lane >> 4, cg = lane & 15;
    int b = pix >> 16, hw = pix & 65535;
    int h = hw >> 8, w = hw & 255;
    float acc = 0.f;
    #pragma unroll
    for (int k = 0; k < 9; ++k) {
        float offy = offs[lp][(g * 9 + k) * 2 + 0];
        float offx = offs[lp][(g * 9 + k) * 2 + 1];
        float mval = ms[lp][g * 9 + k];
        float ly = (float)h + (float)(k / 3 - 1) + offy;
        float lx = (float)w + (float)(k % 3 - 1) + offx;
        float y0f = floorf(ly), x0f = floorf(lx);
        float wy = ly - y0f, wx = lx - x0f;
        int iy0 = (int)y0f, ix0 = (int)x0f;
        #pragma unroll
        for (int dy = 0; dy < 2; ++dy) {
            #pragma unroll
            for (int dx = 0; dx < 2; ++dx) {
                int yi = iy0 + dy, xi = ix0 + dx;
                float wgt = (dy ? wy : 1.f - wy) * (dx ? wx : 1.f - wx);
                float valid = (yi >= 0 && yi < 256 && xi >= 0 && xi < 256) ? 1.f : 0.f;
                int yc = min(max(yi, 0), 255), xc = min(max(xi, 0), 255);
                float v = xg[(((size_t)(b << 16) + (yc << 8) + xc) << 6) + (g << 4) + cg];
                acc += mval * wgt * valid * v;
            }
        }
    }
    accs[lp][lane] = acc;
    __syncthreads();

    // out projection: lane = out channel
    {
        float o = bout[lane];
        #pragma unroll 8
        for (int i = 0; i < 64; ++i) o += accs[lp][i] * Wout[i * 64 + lane];
        outs[lp][lane] = o;
    }
    __syncthreads();

    // transposed NCHW write: thread t -> c = t>>2, wsub = t&3
    int c = tid >> 2, wsub = tid & 3;
    int p0 = blockIdx.x * 4 + wsub;
    int b2 = p0 >> 16, rem = p0 & 65535;
    out[((size_t)b2 * 64 + c) * HW_ + rem] = outs[wsub][c];
}

extern "C" void kernel_launch(void* const* d_in, const int* in_sizes, int n_in,
                              void* d_out, int out_size, void* d_ws, size_t ws_size,
                              hipStream_t stream) {
    const float* x      = (const float*)d_in[0];
    const float* rw1    = (const float*)d_in[1];
    const float* rb1    = (const float*)d_in[2];
    const float* rw2    = (const float*)d_in[3];
    const float* rb2    = (const float*)d_in[4];
    const float* rw3    = (const float*)d_in[5];
    const float* rb3    = (const float*)d_in[6];
    const float* W_in   = (const float*)d_in[7];
    const float* b_in   = (const float*)d_in[8];
    const float* W_aop  = (const float*)d_in[9];
    const float* b_aop  = (const float*)d_in[10];
    const float* dw     = (const float*)d_in[11];
    const float* W_off  = (const float*)d_in[12];
    const float* b_off  = (const float*)d_in[13];
    const float* W_mask = (const float*)d_in[14];
    const float* b_mask = (const float*)d_in[15];
    const float* W_out  = (const float*)d_in[16];
    const float* b_out  = (const float*)d_in[17];
    float* out = (float*)d_out;

    float* ws = (float*)d_ws;
    float* divb  = ws;                      // 131072
    float* u0    = divb + BHW_;             // 131072
    float* u1    = u0 + BHW_;               // 131072
    float* h1    = u1 + BHW_;               // 4194304
    float* h2    = h1 + (size_t)BHW_ * 32;  // 4194304
    float* recon = h2 + (size_t)BHW_ * 32;  // 393216
    float* a     = h1;                      // reuse h1+h2 region (8388608) after convnet
    float* a2    = recon + (size_t)BHW_ * 3; // 8388608
    float* xg    = a2 + (size_t)NPC;         // 8388608

    dim3 blk(256);
    dim3 gpix((BHW_ + 255) / 256);
    dim3 gpc((NPC + 255) / 256);

    k_div<<<gpix, blk, 0, stream>>>(x, divb, u0);
    for (int it = 0; it < 20; ++it) {
        const float* src = (it & 1) ? u1 : u0;
        float* dst = (it & 1) ? u0 : u1;
        k_jacobi<<<gpix, blk, 0, stream>>>(src, divb, dst);
    }
    // gray = u0 after 20 iters
    k_conv1<<<gpix, blk, 0, stream>>>(x, rw1, rb1, h1);
    k_conv2<<<gpix, blk, 0, stream>>>(h1, rw2, rb2, h2);
    k_conv3<<<gpix, blk, 0, stream>>>(h2, rw3, rb3, recon);
    k_aproj<<<gpc, blk, 0, stream>>>(x, W_aop, b_aop, a);
    k_dw<<<gpc, blk, 0, stream>>>(a, dw, a2);
    k_xproj<<<gpc, blk, 0, stream>>>(x, u0, recon, W_in, b_in, xg);
    k_dcn<<<dim3(BHW_ / 4), blk, 0, stream>>>(a2, xg, W_off, b_off, W_mask, b_mask,
                                              W_out, b_out, out);
}